// Round 1
// baseline (1066.865 us; speedup 1.0000x reference)
//
#include <hip/hip_runtime.h>

#define BB 16
#define DD_DIM 512
#define TT 4096
#define KK_DIM 1024

#define BT 128
#define BK 128
#define BD 32
#define NTHREADS 256

// ---------------------------------------------------------------------------
// Kernel 1: c_sq[k] = sum_d codebook[k][d]^2
// ---------------------------------------------------------------------------
__global__ void csq_kernel(const float* __restrict__ cb, float* __restrict__ csq) {
    int wave = threadIdx.x >> 6;
    int lane = threadIdx.x & 63;
    int row  = blockIdx.x * 4 + wave;
    const float* r = cb + (size_t)row * DD_DIM;
    float s = 0.f;
    #pragma unroll
    for (int i = 0; i < DD_DIM / 64; ++i) {
        float v = r[lane + i * 64];
        s += v * v;
    }
    #pragma unroll
    for (int off = 32; off; off >>= 1) s += __shfl_down(s, off, 64);
    if (lane == 0) csq[row] = s;
}

// ---------------------------------------------------------------------------
// Kernel 2: fused GEMM + argmin.
//   score[t][k] = csq[k] - 2 * sum_d x[b][d][t] * cb[k][d]
//   idx_f_out[b][t] = (float)argmin_k score   (first-index tie-break)
// Block: 256 threads, tile BT=128 t's x BK=128 k's, 8x8 acc per thread.
// ---------------------------------------------------------------------------
__global__ __launch_bounds__(NTHREADS) void argmin_kernel(
    const float* __restrict__ x, const float* __restrict__ cb,
    const float* __restrict__ csq, float* __restrict__ idx_f_out) {

    __shared__ float xs[BD][BT];        // 16 KiB, x tile: [d][t]
    __shared__ float cs[BD][BK + 4];    // ~16.5 KiB, cb tile transposed: [d][k], +4 pad

    const int tid   = threadIdx.x;
    const int b     = blockIdx.y;
    const int t_blk = blockIdx.x * BT;
    const int tq = tid & 15;   // t-group (16 groups)
    const int kq = tid >> 4;   // k-group (16 groups)
    const int t0 = tq * 8;
    const int k0 = kq * 8;

    const float* xb = x + (size_t)b * DD_DIM * TT;

    float best[8];
    int   bidx[8];
    #pragma unroll
    for (int i = 0; i < 8; ++i) { best[i] = 3.4e38f; bidx[i] = 0; }

    for (int kc = 0; kc < KK_DIM; kc += BK) {
        float acc[8][8];
        #pragma unroll
        for (int i = 0; i < 8; ++i)
            #pragma unroll
            for (int j = 0; j < 8; ++j) acc[i][j] = 0.f;

        for (int dc = 0; dc < DD_DIM; dc += BD) {
            __syncthreads();
            // stage x tile: BD x BT floats = 1024 float4, 4 per thread, coalesced
            #pragma unroll
            for (int j = 0; j < 4; ++j) {
                int i4 = tid + NTHREADS * j;
                int dd = i4 >> 5;           // 32 float4 per row
                int tp = (i4 & 31) << 2;
                float4 v = *(const float4*)(xb + (size_t)(dc + dd) * TT + t_blk + tp);
                *(float4*)&xs[dd][tp] = v;
            }
            // stage cb tile transposed: read float4 along d, scatter into [d][k]
            #pragma unroll
            for (int j = 0; j < 4; ++j) {
                int i4 = tid + NTHREADS * j;
                int kk = i4 >> 3;           // 8 float4 per codebook-row chunk
                int dq = (i4 & 7) << 2;
                float4 v = *(const float4*)(cb + (size_t)(kc + kk) * DD_DIM + dc + dq);
                cs[dq + 0][kk] = v.x;
                cs[dq + 1][kk] = v.y;
                cs[dq + 2][kk] = v.z;
                cs[dq + 3][kk] = v.w;
            }
            __syncthreads();

            #pragma unroll 8
            for (int dd = 0; dd < BD; ++dd) {
                float a[8], bv[8];
                *(float4*)&a[0]  = *(const float4*)&xs[dd][t0];
                *(float4*)&a[4]  = *(const float4*)&xs[dd][t0 + 4];
                *(float4*)&bv[0] = *(const float4*)&cs[dd][k0];
                *(float4*)&bv[4] = *(const float4*)&cs[dd][k0 + 4];
                #pragma unroll
                for (int i = 0; i < 8; ++i)
                    #pragma unroll
                    for (int j = 0; j < 8; ++j)
                        acc[i][j] = fmaf(a[i], bv[j], acc[i][j]);
            }
        }
        // epilogue: fold this k-chunk into running best (k ascending => strict <
        // preserves first-index tie-break within a thread)
        #pragma unroll
        for (int j = 0; j < 8; ++j) {
            int   kg = kc + k0 + j;
            float cq = csq[kg];
            #pragma unroll
            for (int i = 0; i < 8; ++i) {
                float s = cq - 2.0f * acc[i][j];
                if (s < best[i]) { best[i] = s; bidx[i] = kg; }
            }
        }
    }

    // cross-thread reduction over the 16 k-groups (alias tile LDS)
    __syncthreads();
    float* rbest = &xs[0][0];          // [16][BT]
    int*   ridx  = (int*)&xs[16][0];   // [16][BT]
    #pragma unroll
    for (int i = 0; i < 8; ++i) {
        rbest[kq * BT + t0 + i] = best[i];
        ridx [kq * BT + t0 + i] = bidx[i];
    }
    __syncthreads();
    if (tid < BT) {
        float bv = rbest[tid];
        int   bi = ridx[tid];
        #pragma unroll
        for (int g = 1; g < 16; ++g) {
            float v  = rbest[g * BT + tid];
            int   ii = ridx [g * BT + tid];
            if (v < bv || (v == bv && ii < bi)) { bv = v; bi = ii; }
        }
        int t = t_blk + tid;
        idx_f_out[(size_t)b * TT + t] = (float)bi;
    }
}

// ---------------------------------------------------------------------------
// Kernel 3: quantized[b][d][t] = codebook[idx[b][t]][d]
// Reads the float-encoded indexes (exact for k < 2^24).
// Writes coalesced in t; codebook rows come from L1/L2.
// ---------------------------------------------------------------------------
__global__ void gather_kernel(const float* __restrict__ cb,
                              const float* __restrict__ idx_f,
                              float* __restrict__ out) {
    int b  = blockIdx.y;
    int t  = blockIdx.x * 256 + threadIdx.x;
    int d0 = blockIdx.z * (DD_DIM / 4);
    int k  = (int)idx_f[(size_t)b * TT + t];
    const float* row = cb + (size_t)k * DD_DIM;
    float* ob = out + (size_t)b * DD_DIM * TT + t;
    #pragma unroll 8
    for (int d = d0; d < d0 + DD_DIM / 4; ++d)
        ob[(size_t)d * TT] = row[d];
}

extern "C" void kernel_launch(void* const* d_in, const int* in_sizes, int n_in,
                              void* d_out, int out_size, void* d_ws, size_t ws_size,
                              hipStream_t stream) {
    const float* x  = (const float*)d_in[0];
    const float* cb = (const float*)d_in[1];
    float* out   = (float*)d_out;                      // quantized [B*D*T]
    float* idx_f = out + (size_t)BB * DD_DIM * TT;     // indexes as float [B*T]
    float* csq   = (float*)d_ws;                       // K floats scratch

    csq_kernel<<<KK_DIM / 4, 256, 0, stream>>>(cb, csq);

    dim3 g2(TT / BT, BB);
    argmin_kernel<<<g2, NTHREADS, 0, stream>>>(x, cb, csq, idx_f);

    dim3 g3(TT / 256, BB, 4);
    gather_kernel<<<g3, 256, 0, stream>>>(cb, idx_f, out);
}

// Round 2
// 510.839 us; speedup vs baseline: 2.0885x; 2.0885x over previous
//
#include <hip/hip_runtime.h>

#define BB 16
#define DD 512
#define TT 4096
#define KK 1024

typedef _Float16 h16;
typedef __attribute__((ext_vector_type(8))) _Float16 half8;
typedef __attribute__((ext_vector_type(4))) float float4v;

// ---- ws layout (main path), bytes ----
#define XTH_OFF 0ull
#define XTL_OFF 67108864ull          // B*T*D*2 = 64 MiB per plane
#define CBH_OFF 134217728ull
#define CBL_OFF 135266304ull         // + K*D*2 = 1 MiB
#define CSQ_OFF 136314880ull
#define WS_NEED (136314880ull + 4096ull)

#define GLOAD_LDS16(g, l) __builtin_amdgcn_global_load_lds( \
    (const __attribute__((address_space(1))) void*)(g),      \
    (__attribute__((address_space(3))) void*)(l), 16, 0, 0)

// ---------------------------------------------------------------------------
// csq[k] = sum_d cb[k][d]^2
// ---------------------------------------------------------------------------
__global__ void csq_kernel(const float* __restrict__ cb, float* __restrict__ csq) {
    int wave = threadIdx.x >> 6;
    int lane = threadIdx.x & 63;
    int row  = blockIdx.x * 4 + wave;
    const float* r = cb + (size_t)row * DD;
    float s = 0.f;
    #pragma unroll
    for (int i = 0; i < DD / 64; ++i) { float v = r[lane + i * 64]; s += v * v; }
    #pragma unroll
    for (int off = 32; off; off >>= 1) s += __shfl_down(s, off, 64);
    if (lane == 0) csq[row] = s;
}

// ---------------------------------------------------------------------------
// split x [B][D][T] fp32 -> xt_h, xt_l [B][T][D] f16 (transpose via LDS)
// ---------------------------------------------------------------------------
__global__ __launch_bounds__(256) void split_x_kernel(const float* __restrict__ x,
                                                      h16* __restrict__ xth,
                                                      h16* __restrict__ xtl) {
    __shared__ float xs[64][68];   // +4 pad: 16B-aligned rows, rotated banks
    const int b = blockIdx.z, d0 = blockIdx.y * 64, t0 = blockIdx.x * 64;
    const int tid = threadIdx.x;
    const float* xp = x + ((size_t)b * DD + d0) * TT + t0;
    #pragma unroll
    for (int j = 0; j < 4; ++j) {
        int i4 = tid + 256 * j;
        int dd = i4 >> 4, tp = (i4 & 15) << 2;
        float4 v = *(const float4*)(xp + (size_t)dd * TT + tp);
        *(float4*)&xs[dd][tp] = v;
    }
    __syncthreads();
    const int tt = tid & 63, dq = (tid >> 6) << 4;
    h16 hv[16], lv[16];
    #pragma unroll
    for (int i = 0; i < 16; ++i) {
        float v = xs[dq + i][tt];
        h16 h = (h16)v;
        hv[i] = h;
        lv[i] = (h16)(v - (float)h);
    }
    size_t o = ((size_t)b * TT + t0 + tt) * DD + d0 + dq;
    *(half8*)(xth + o)     = *(half8*)&hv[0];
    *(half8*)(xth + o + 8) = *(half8*)&hv[8];
    *(half8*)(xtl + o)     = *(half8*)&lv[0];
    *(half8*)(xtl + o + 8) = *(half8*)&lv[8];
}

// ---------------------------------------------------------------------------
// split cb [K][D] fp32 -> cb_h, cb_l f16 (same layout)
// ---------------------------------------------------------------------------
__global__ void split_cb_kernel(const float* __restrict__ cb,
                                h16* __restrict__ cbh, h16* __restrict__ cbl) {
    int g = blockIdx.x * 256 + threadIdx.x;      // one float4 per thread
    float4 v = *(const float4*)(cb + (size_t)g * 4);
    h16 h[4], l[4];
    float vv[4] = {v.x, v.y, v.z, v.w};
    #pragma unroll
    for (int i = 0; i < 4; ++i) {
        h[i] = (h16)vv[i];
        l[i] = (h16)(vv[i] - (float)h[i]);
    }
    *(ushort4*)(cbh + (size_t)g * 4) = *(ushort4*)h;
    *(ushort4*)(cbl + (size_t)g * 4) = *(ushort4*)l;
}

// ---------------------------------------------------------------------------
// fused f16x3-split MFMA GEMM + argmin.
// score[t][k] = csq[k] - 2 * (xh.bh + xh.bl + xl.bh)
// 128 t x 128 k tile per block, 4 waves in 2x2, argmin folded per k-chunk.
// ---------------------------------------------------------------------------
__global__ __launch_bounds__(256, 2) void mfma_argmin_kernel(
    const h16* __restrict__ xth, const h16* __restrict__ xtl,
    const h16* __restrict__ cbh, const h16* __restrict__ cbl,
    const float* __restrict__ csq, float* __restrict__ idx_f_out) {

    __shared__ h16 ash[128 * 64];
    __shared__ h16 asl[128 * 64];
    __shared__ h16 bsh[128 * 64];
    __shared__ h16 bsl[128 * 64];
    __shared__ float redv[2][128];
    __shared__ int   redi[2][128];

    const int tid = threadIdx.x;
    const int wid = tid >> 6, lane = tid & 63;
    const int wm = wid & 1, wn = wid >> 1;
    const int b = blockIdx.y, t0 = blockIdx.x * 128;
    const int lr = lane >> 3;          // staging: row within 8-row group
    const int lc = (lane & 7) * 8;     // staging: col offset (halfs)
    const int c  = lane & 15;          // frag col (n / k_cb)
    const int q  = lane >> 4;          // frag quad

    const h16* xhb = xth + ((size_t)b * TT + t0) * DD;
    const h16* xlb = xtl + ((size_t)b * TT + t0) * DD;

    float best[16];
    int   bidx[16];
    #pragma unroll
    for (int i = 0; i < 16; ++i) { best[i] = 3.4e38f; bidx[i] = 0; }

    for (int kc = 0; kc < KK; kc += 128) {
        float4v acc[4][4];
        #pragma unroll
        for (int m = 0; m < 4; ++m)
            #pragma unroll
            for (int n = 0; n < 4; ++n)
                acc[m][n] = (float4v){0.f, 0.f, 0.f, 0.f};

        for (int dc = 0; dc < DD; dc += 64) {
            __syncthreads();
            const int rbase = wid * 32;
            #pragma unroll
            for (int i = 0; i < 4; ++i) {
                int r = rbase + i * 8;
                GLOAD_LDS16(xhb + (size_t)(r + lr) * DD + dc + lc, ash + r * 64);
                GLOAD_LDS16(xlb + (size_t)(r + lr) * DD + dc + lc, asl + r * 64);
                GLOAD_LDS16(cbh + (size_t)(kc + r + lr) * DD + dc + lc, bsh + r * 64);
                GLOAD_LDS16(cbl + (size_t)(kc + r + lr) * DD + dc + lc, bsl + r * 64);
            }
            __syncthreads();

            #pragma unroll
            for (int ks = 0; ks < 2; ++ks) {
                const int doff = ks * 32 + q * 8;
                half8 Ah[4], Al[4];
                #pragma unroll
                for (int m = 0; m < 4; ++m) {
                    int row = wm * 64 + m * 16 + c;
                    Ah[m] = *(const half8*)(ash + row * 64 + doff);
                    Al[m] = *(const half8*)(asl + row * 64 + doff);
                }
                #pragma unroll
                for (int n = 0; n < 4; ++n) {
                    int row = wn * 64 + n * 16 + c;
                    half8 Bh = *(const half8*)(bsh + row * 64 + doff);
                    half8 Bl = *(const half8*)(bsl + row * 64 + doff);
                    #pragma unroll
                    for (int m = 0; m < 4; ++m) {
                        acc[m][n] = __builtin_amdgcn_mfma_f32_16x16x32_f16(Ah[m], Bh, acc[m][n], 0, 0, 0);
                        acc[m][n] = __builtin_amdgcn_mfma_f32_16x16x32_f16(Ah[m], Bl, acc[m][n], 0, 0, 0);
                        acc[m][n] = __builtin_amdgcn_mfma_f32_16x16x32_f16(Al[m], Bh, acc[m][n], 0, 0, 0);
                    }
                }
            }
        }
        // fold k-chunk into running argmin (k ascending across kc and n)
        #pragma unroll
        for (int n = 0; n < 4; ++n) {
            int kg = kc + wn * 64 + n * 16 + c;
            float cq = csq[kg];
            #pragma unroll
            for (int m = 0; m < 4; ++m)
                #pragma unroll
                for (int r = 0; r < 4; ++r) {
                    float s = fmaf(-2.0f, acc[m][n][r], cq);
                    int slot = m * 4 + r;
                    if (s < best[slot]) { best[slot] = s; bidx[slot] = kg; }
                }
        }
    }

    // reduce over the 16 frag columns (lanes sharing a t)
    #pragma unroll
    for (int slot = 0; slot < 16; ++slot) {
        float v = best[slot]; int i = bidx[slot];
        #pragma unroll
        for (int d = 1; d < 16; d <<= 1) {
            float pv = __shfl_xor(v, d);
            int   pi = __shfl_xor(i, d);
            if (pv < v || (pv == v && pi < i)) { v = pv; i = pi; }
        }
        if (c == 0) {
            int m = slot >> 2, r = slot & 3;
            int tl = wm * 64 + m * 16 + q * 4 + r;
            redv[wn][tl] = v; redi[wn][tl] = i;
        }
    }
    __syncthreads();
    if (tid < 128) {
        float v0 = redv[0][tid]; int i0 = redi[0][tid];
        float v1 = redv[1][tid]; int i1 = redi[1][tid];
        if (v1 < v0 || (v1 == v0 && i1 < i0)) { v0 = v1; i0 = i1; }
        idx_f_out[(size_t)b * TT + t0 + tid] = (float)i0;
    }
}

// ---------------------------------------------------------------------------
// gather: quantized[b][d][t] = cb[idx[b][t]][d]
// ---------------------------------------------------------------------------
__global__ void gather_kernel(const float* __restrict__ cb,
                              const float* __restrict__ idx_f,
                              float* __restrict__ out) {
    int b  = blockIdx.y;
    int t  = blockIdx.x * 256 + threadIdx.x;
    int d0 = blockIdx.z * (DD / 4);
    int k  = (int)idx_f[(size_t)b * TT + t];
    const float* row = cb + (size_t)k * DD;
    float* ob = out + (size_t)b * DD * TT + t;
    #pragma unroll 8
    for (int d = d0; d < d0 + DD / 4; ++d)
        ob[(size_t)d * TT] = row[d];
}

// ---------------------------------------------------------------------------
// fallback fp32 path (round-1 kernel) in case ws is too small for the splits
// ---------------------------------------------------------------------------
__global__ __launch_bounds__(256) void argmin_fp32_kernel(
    const float* __restrict__ x, const float* __restrict__ cb,
    const float* __restrict__ csq, float* __restrict__ idx_f_out) {

    __shared__ float xs[32][128];
    __shared__ float cs[32][132];

    const int tid = threadIdx.x;
    const int b = blockIdx.y;
    const int t_blk = blockIdx.x * 128;
    const int tq = tid & 15, kq = tid >> 4;
    const int t0 = tq * 8, k0 = kq * 8;
    const float* xb = x + (size_t)b * DD * TT;

    float best[8]; int bidx[8];
    #pragma unroll
    for (int i = 0; i < 8; ++i) { best[i] = 3.4e38f; bidx[i] = 0; }

    for (int kc = 0; kc < KK; kc += 128) {
        float acc[8][8];
        #pragma unroll
        for (int i = 0; i < 8; ++i)
            #pragma unroll
            for (int j = 0; j < 8; ++j) acc[i][j] = 0.f;
        for (int dc = 0; dc < DD; dc += 32) {
            __syncthreads();
            #pragma unroll
            for (int j = 0; j < 4; ++j) {
                int i4 = tid + 256 * j;
                int dd = i4 >> 5, tp = (i4 & 31) << 2;
                *(float4*)&xs[dd][tp] =
                    *(const float4*)(xb + (size_t)(dc + dd) * TT + t_blk + tp);
            }
            #pragma unroll
            for (int j = 0; j < 4; ++j) {
                int i4 = tid + 256 * j;
                int kk = i4 >> 3, dq = (i4 & 7) << 2;
                float4 v = *(const float4*)(cb + (size_t)(kc + kk) * DD + dc + dq);
                cs[dq + 0][kk] = v.x; cs[dq + 1][kk] = v.y;
                cs[dq + 2][kk] = v.z; cs[dq + 3][kk] = v.w;
            }
            __syncthreads();
            #pragma unroll 8
            for (int dd = 0; dd < 32; ++dd) {
                float a[8], bv[8];
                *(float4*)&a[0]  = *(const float4*)&xs[dd][t0];
                *(float4*)&a[4]  = *(const float4*)&xs[dd][t0 + 4];
                *(float4*)&bv[0] = *(const float4*)&cs[dd][k0];
                *(float4*)&bv[4] = *(const float4*)&cs[dd][k0 + 4];
                #pragma unroll
                for (int i = 0; i < 8; ++i)
                    #pragma unroll
                    for (int j = 0; j < 8; ++j)
                        acc[i][j] = fmaf(a[i], bv[j], acc[i][j]);
            }
        }
        #pragma unroll
        for (int j = 0; j < 8; ++j) {
            int kg = kc + k0 + j;
            float cq = csq[kg];
            #pragma unroll
            for (int i = 0; i < 8; ++i) {
                float s = cq - 2.0f * acc[i][j];
                if (s < best[i]) { best[i] = s; bidx[i] = kg; }
            }
        }
    }
    __syncthreads();
    float* rbest = &xs[0][0];
    int*   ridx  = (int*)&cs[0][0];
    #pragma unroll
    for (int i = 0; i < 8; ++i) {
        rbest[kq * 128 + t0 + i] = best[i];
        ridx [kq * 128 + t0 + i] = bidx[i];
    }
    __syncthreads();
    if (tid < 128) {
        float bv = rbest[tid]; int bi = ridx[tid];
        #pragma unroll
        for (int g = 1; g < 16; ++g) {
            float v = rbest[g * 128 + tid]; int ii = ridx[g * 128 + tid];
            if (v < bv || (v == bv && ii < bi)) { bv = v; bi = ii; }
        }
        idx_f_out[(size_t)b * TT + t_blk + tid] = (float)bi;
    }
}

extern "C" void kernel_launch(void* const* d_in, const int* in_sizes, int n_in,
                              void* d_out, int out_size, void* d_ws, size_t ws_size,
                              hipStream_t stream) {
    const float* x  = (const float*)d_in[0];
    const float* cb = (const float*)d_in[1];
    float* out   = (float*)d_out;
    float* idx_f = out + (size_t)BB * DD * TT;

    if (ws_size >= WS_NEED) {
        h16* xth = (h16*)((char*)d_ws + XTH_OFF);
        h16* xtl = (h16*)((char*)d_ws + XTL_OFF);
        h16* cbh = (h16*)((char*)d_ws + CBH_OFF);
        h16* cbl = (h16*)((char*)d_ws + CBL_OFF);
        float* csq = (float*)((char*)d_ws + CSQ_OFF);

        csq_kernel<<<KK / 4, 256, 0, stream>>>(cb, csq);
        split_cb_kernel<<<(KK * DD / 4) / 256, 256, 0, stream>>>(cb, cbh, cbl);
        split_x_kernel<<<dim3(TT / 64, DD / 64, BB), 256, 0, stream>>>(x, xth, xtl);
        mfma_argmin_kernel<<<dim3(TT / 128, BB), 256, 0, stream>>>(
            xth, xtl, cbh, cbl, csq, idx_f);
        gather_kernel<<<dim3(TT / 256, BB, 4), 256, 0, stream>>>(cb, idx_f, out);
    } else {
        float* csq = (float*)d_ws;
        csq_kernel<<<KK / 4, 256, 0, stream>>>(cb, csq);
        argmin_fp32_kernel<<<dim3(TT / 128, BB), 256, 0, stream>>>(x, cb, csq, idx_f);
        gather_kernel<<<dim3(TT / 256, BB, 4), 256, 0, stream>>>(cb, idx_f, out);
    }
}

// Round 3
// 486.292 us; speedup vs baseline: 2.1939x; 1.0505x over previous
//
#include <hip/hip_runtime.h>

#define BB 16
#define DD 512
#define TT 4096
#define KK 1024

typedef _Float16 h16;
typedef __attribute__((ext_vector_type(8))) _Float16 half8;
typedef __attribute__((ext_vector_type(4))) float float4v;

// ---- ws layout (main path), bytes ----
// xth/xtl tiled: [b][tb(32)][dcb(16)][128][32] halfs -> 64 MiB per plane
// cbh/cbl tiled: [kb(8)][dcb(16)][128][32] halfs    -> 1 MiB per plane
#define XTH_OFF 0ull
#define XTL_OFF 67108864ull
#define CBH_OFF 134217728ull
#define CBL_OFF 135266304ull
#define CSQ_OFF 136314880ull
#define WS_NEED (136314880ull + 4096ull)

#define GLOAD_LDS16(g, l) __builtin_amdgcn_global_load_lds( \
    (const __attribute__((address_space(1))) void*)(g),      \
    (__attribute__((address_space(3))) void*)(l), 16, 0, 0)

// ---------------------------------------------------------------------------
// csq[k] = sum_d cb[k][d]^2
// ---------------------------------------------------------------------------
__global__ void csq_kernel(const float* __restrict__ cb, float* __restrict__ csq) {
    int wave = threadIdx.x >> 6;
    int lane = threadIdx.x & 63;
    int row  = blockIdx.x * 4 + wave;
    const float* r = cb + (size_t)row * DD;
    float s = 0.f;
    #pragma unroll
    for (int i = 0; i < DD / 64; ++i) { float v = r[lane + i * 64]; s += v * v; }
    #pragma unroll
    for (int off = 32; off; off >>= 1) s += __shfl_down(s, off, 64);
    if (lane == 0) csq[row] = s;
}

// ---------------------------------------------------------------------------
// split x [B][D][T] fp32 -> tiled f16 planes [b][tb][dcb][128][32].
// Block = one (b, tb, dcb) chunk: reads 32d x 128t coalesced, LDS transpose
// (2-way conflicts only), writes 8 KiB contiguous per plane.
// ---------------------------------------------------------------------------
__global__ __launch_bounds__(256) void split_x_kernel(const float* __restrict__ x,
                                                      h16* __restrict__ xth,
                                                      h16* __restrict__ xtl) {
    __shared__ float xs[32][132];  // float4-stored rows, 16B-aligned stride
    const int tb = blockIdx.x, dcb = blockIdx.y, b = blockIdx.z;
    const int tid = threadIdx.x;
    const int t0 = tb * 128, d0 = dcb * 32;
    const float* xp = x + ((size_t)b * DD + d0) * TT + t0;
    #pragma unroll
    for (int j = 0; j < 4; ++j) {
        int i4 = tid + 256 * j;
        int dd = i4 >> 5, c4 = (i4 & 31) << 2;
        *(float4*)&xs[dd][c4] = *(const float4*)(xp + (size_t)dd * TT + c4);
    }
    __syncthreads();
    const int r = tid >> 1;              // t-local row of output
    const int ch = (tid & 1) * 16;       // d-half
    h16 hv[16], lv[16];
    #pragma unroll
    for (int i = 0; i < 16; ++i) {
        float v = xs[ch + i][r];
        h16 h = (h16)v;
        hv[i] = h;
        lv[i] = (h16)(v - (float)h);
    }
    size_t o = (((size_t)(b * 32 + tb) * 16) + dcb) * 4096 + (size_t)tid * 16;
    *(half8*)(xth + o)     = *(half8*)&hv[0];
    *(half8*)(xth + o + 8) = *(half8*)&hv[8];
    *(half8*)(xtl + o)     = *(half8*)&lv[0];
    *(half8*)(xtl + o + 8) = *(half8*)&lv[8];
}

// ---------------------------------------------------------------------------
// split cb [K][D] fp32 -> tiled f16 planes [kb][dcb][128][32]. No transpose.
// Block = one (kb, dcb) chunk.
// ---------------------------------------------------------------------------
__global__ __launch_bounds__(256) void split_cb_kernel(const float* __restrict__ cb,
                                                       h16* __restrict__ cbh,
                                                       h16* __restrict__ cbl) {
    const int kb = blockIdx.x >> 4, dcb = blockIdx.x & 15;
    const int tid = threadIdx.x;
    const float* cp = cb + ((size_t)kb * 128) * DD + dcb * 32;
    h16* oh = cbh + ((size_t)(kb * 16 + dcb)) * 4096;
    h16* ol = cbl + ((size_t)(kb * 16 + dcb)) * 4096;
    #pragma unroll
    for (int j = 0; j < 4; ++j) {
        int i4 = tid + 256 * j;
        int rr = i4 >> 3, c4 = (i4 & 7) << 2;
        float4 v = *(const float4*)(cp + (size_t)rr * DD + c4);
        float vv[4] = {v.x, v.y, v.z, v.w};
        h16 h[4], l[4];
        #pragma unroll
        for (int i = 0; i < 4; ++i) {
            h[i] = (h16)vv[i];
            l[i] = (h16)(vv[i] - (float)h[i]);
        }
        *(ushort4*)(oh + rr * 32 + c4) = *(ushort4*)h;
        *(ushort4*)(ol + rr * 32 + c4) = *(ushort4*)l;
    }
}

// ---------------------------------------------------------------------------
// fused f16x3-split MFMA GEMM + argmin + gather.
// score[t][k] = csq[k] - 2 * (xh.bh + xh.bl + xl.bh)
// 128t x 128k tile, 4 waves 2x2, BD=32 (32 KiB tiles -> 3 blocks/CU).
// Epilogue writes quantized[b][:,t0:t0+128] directly.
// ---------------------------------------------------------------------------
__global__ __launch_bounds__(256, 3) void mfma_argmin_kernel(
    const h16* __restrict__ xth, const h16* __restrict__ xtl,
    const h16* __restrict__ cbh, const h16* __restrict__ cbl,
    const float* __restrict__ csq, const float* __restrict__ cb,
    float* __restrict__ idx_f_out, float* __restrict__ out) {

    __shared__ h16 ash[4096];
    __shared__ h16 asl[4096];
    __shared__ h16 bsh[4096];
    __shared__ h16 bsl[4096];
    __shared__ float redv[2][128];
    __shared__ int   redi[2][128];

    const int tid = threadIdx.x;
    const int wid = tid >> 6, lane = tid & 63;
    const int wm = wid & 1, wn = wid >> 1;
    const int tb = blockIdx.x, b = blockIdx.y;
    const int t0 = tb * 128;
    const int c  = lane & 15;          // frag col
    const int q  = lane >> 4;          // frag quad

    const h16* aH = xth + ((size_t)(b * 32 + tb) * 16) * 4096;
    const h16* aL = xtl + ((size_t)(b * 32 + tb) * 16) * 4096;

    float best[16];
    int   bidx[16];
    #pragma unroll
    for (int i = 0; i < 16; ++i) { best[i] = 3.4e38f; bidx[i] = 0; }

    for (int kci = 0; kci < 8; ++kci) {
        const h16* bH = cbh + (size_t)kci * 16 * 4096;
        const h16* bL = cbl + (size_t)kci * 16 * 4096;
        float4v acc[4][4];
        #pragma unroll
        for (int m = 0; m < 4; ++m)
            #pragma unroll
            for (int n = 0; n < 4; ++n)
                acc[m][n] = (float4v){0.f, 0.f, 0.f, 0.f};

        for (int dcb = 0; dcb < 16; ++dcb) {
            __syncthreads();
            #pragma unroll
            for (int j = 0; j < 2; ++j) {
                int off = (tid + 256 * j) * 8;
                GLOAD_LDS16(aH + (size_t)dcb * 4096 + off, ash + off);
                GLOAD_LDS16(aL + (size_t)dcb * 4096 + off, asl + off);
                GLOAD_LDS16(bH + (size_t)dcb * 4096 + off, bsh + off);
                GLOAD_LDS16(bL + (size_t)dcb * 4096 + off, bsl + off);
            }
            __syncthreads();

            const int doff = q * 8;
            half8 Ah[4], Al[4];
            #pragma unroll
            for (int m = 0; m < 4; ++m) {
                int row = wm * 64 + m * 16 + c;
                Ah[m] = *(const half8*)(ash + row * 32 + doff);
                Al[m] = *(const half8*)(asl + row * 32 + doff);
            }
            #pragma unroll
            for (int n = 0; n < 4; ++n) {
                int row = wn * 64 + n * 16 + c;
                half8 Bh = *(const half8*)(bsh + row * 32 + doff);
                half8 Bl = *(const half8*)(bsl + row * 32 + doff);
                #pragma unroll
                for (int m = 0; m < 4; ++m) {
                    acc[m][n] = __builtin_amdgcn_mfma_f32_16x16x32_f16(Ah[m], Bh, acc[m][n], 0, 0, 0);
                    acc[m][n] = __builtin_amdgcn_mfma_f32_16x16x32_f16(Ah[m], Bl, acc[m][n], 0, 0, 0);
                    acc[m][n] = __builtin_amdgcn_mfma_f32_16x16x32_f16(Al[m], Bh, acc[m][n], 0, 0, 0);
                }
            }
        }
        // fold k-chunk into running argmin (k ascending => first-index tie-break)
        #pragma unroll
        for (int n = 0; n < 4; ++n) {
            int kg = kci * 128 + wn * 64 + n * 16 + c;
            float cq = csq[kg];
            #pragma unroll
            for (int m = 0; m < 4; ++m)
                #pragma unroll
                for (int r = 0; r < 4; ++r) {
                    float s = fmaf(-2.0f, acc[m][n][r], cq);
                    int slot = m * 4 + r;
                    if (s < best[slot]) { best[slot] = s; bidx[slot] = kg; }
                }
        }
    }

    // reduce over the 16 frag columns (lanes sharing a t)
    #pragma unroll
    for (int slot = 0; slot < 16; ++slot) {
        float v = best[slot]; int i = bidx[slot];
        #pragma unroll
        for (int d = 1; d < 16; d <<= 1) {
            float pv = __shfl_xor(v, d);
            int   pi = __shfl_xor(i, d);
            if (pv < v || (pv == v && pi < i)) { v = pv; i = pi; }
        }
        if (c == 0) {
            int m = slot >> 2, r = slot & 3;
            int tl = wm * 64 + m * 16 + q * 4 + r;
            redv[wn][tl] = v; redi[wn][tl] = i;
        }
    }
    __syncthreads();
    if (tid < 128) {
        float v0 = redv[0][tid]; int i0 = redi[0][tid];
        float v1 = redv[1][tid]; int i1 = redi[1][tid];
        if (v1 < v0 || (v1 == v0 && i1 < i0)) { v0 = v1; i0 = i1; }
        idx_f_out[(size_t)b * TT + t0 + tid] = (float)i0;
        redi[0][tid] = i0;                 // broadcast final index
    }
    __syncthreads();

    // fused gather: out[b][d][t0+tl] = cb[k][d]
    const int tl = tid & 127, dg = tid >> 7;
    const int k = redi[0][tl];
    const float* row = cb + (size_t)k * DD + dg * 256;
    float* ob = out + ((size_t)b * DD + dg * 256) * TT + t0 + tl;
    #pragma unroll 4
    for (int i = 0; i < 64; ++i) {
        float4 v = *(const float4*)(row + i * 4);
        ob[(size_t)(i * 4 + 0) * TT] = v.x;
        ob[(size_t)(i * 4 + 1) * TT] = v.y;
        ob[(size_t)(i * 4 + 2) * TT] = v.z;
        ob[(size_t)(i * 4 + 3) * TT] = v.w;
    }
}

// ---------------------------------------------------------------------------
// fallback fp32 path + standalone gather (used only if ws too small)
// ---------------------------------------------------------------------------
__global__ void gather_kernel(const float* __restrict__ cb,
                              const float* __restrict__ idx_f,
                              float* __restrict__ out) {
    int b  = blockIdx.y;
    int t  = blockIdx.x * 256 + threadIdx.x;
    int d0 = blockIdx.z * (DD / 4);
    int k  = (int)idx_f[(size_t)b * TT + t];
    const float* row = cb + (size_t)k * DD;
    float* ob = out + (size_t)b * DD * TT + t;
    #pragma unroll 8
    for (int d = d0; d < d0 + DD / 4; ++d)
        ob[(size_t)d * TT] = row[d];
}

__global__ __launch_bounds__(256) void argmin_fp32_kernel(
    const float* __restrict__ x, const float* __restrict__ cb,
    const float* __restrict__ csq, float* __restrict__ idx_f_out) {

    __shared__ float xs[32][128];
    __shared__ float cs[32][132];

    const int tid = threadIdx.x;
    const int b = blockIdx.y;
    const int t_blk = blockIdx.x * 128;
    const int tq = tid & 15, kq = tid >> 4;
    const int t0 = tq * 8, k0 = kq * 8;
    const float* xb = x + (size_t)b * DD * TT;

    float best[8]; int bidx[8];
    #pragma unroll
    for (int i = 0; i < 8; ++i) { best[i] = 3.4e38f; bidx[i] = 0; }

    for (int kc = 0; kc < KK; kc += 128) {
        float acc[8][8];
        #pragma unroll
        for (int i = 0; i < 8; ++i)
            #pragma unroll
            for (int j = 0; j < 8; ++j) acc[i][j] = 0.f;
        for (int dc = 0; dc < DD; dc += 32) {
            __syncthreads();
            #pragma unroll
            for (int j = 0; j < 4; ++j) {
                int i4 = tid + 256 * j;
                int dd = i4 >> 5, tp = (i4 & 31) << 2;
                *(float4*)&xs[dd][tp] =
                    *(const float4*)(xb + (size_t)(dc + dd) * TT + t_blk + tp);
            }
            #pragma unroll
            for (int j = 0; j < 4; ++j) {
                int i4 = tid + 256 * j;
                int kk = i4 >> 3, dq = (i4 & 7) << 2;
                float4 v = *(const float4*)(cb + (size_t)(kc + kk) * DD + dc + dq);
                cs[dq + 0][kk] = v.x; cs[dq + 1][kk] = v.y;
                cs[dq + 2][kk] = v.z; cs[dq + 3][kk] = v.w;
            }
            __syncthreads();
            #pragma unroll 8
            for (int dd = 0; dd < 32; ++dd) {
                float a[8], bv[8];
                *(float4*)&a[0]  = *(const float4*)&xs[dd][t0];
                *(float4*)&a[4]  = *(const float4*)&xs[dd][t0 + 4];
                *(float4*)&bv[0] = *(const float4*)&cs[dd][k0];
                *(float4*)&bv[4] = *(const float4*)&cs[dd][k0 + 4];
                #pragma unroll
                for (int i = 0; i < 8; ++i)
                    #pragma unroll
                    for (int j = 0; j < 8; ++j)
                        acc[i][j] = fmaf(a[i], bv[j], acc[i][j]);
            }
        }
        #pragma unroll
        for (int j = 0; j < 8; ++j) {
            int kg = kc + k0 + j;
            float cq = csq[kg];
            #pragma unroll
            for (int i = 0; i < 8; ++i) {
                float s = cq - 2.0f * acc[i][j];
                if (s < best[i]) { best[i] = s; bidx[i] = kg; }
            }
        }
    }
    __syncthreads();
    float* rbest = &xs[0][0];
    int*   ridx  = (int*)&cs[0][0];
    #pragma unroll
    for (int i = 0; i < 8; ++i) {
        rbest[kq * 128 + t0 + i] = best[i];
        ridx [kq * 128 + t0 + i] = bidx[i];
    }
    __syncthreads();
    if (tid < 128) {
        float bv = rbest[tid]; int bi = ridx[tid];
        #pragma unroll
        for (int g = 1; g < 16; ++g) {
            float v = rbest[g * 128 + tid]; int ii = ridx[g * 128 + tid];
            if (v < bv || (v == bv && ii < bi)) { bv = v; bi = ii; }
        }
        idx_f_out[(size_t)b * TT + t_blk + tid] = (float)bi;
    }
}

extern "C" void kernel_launch(void* const* d_in, const int* in_sizes, int n_in,
                              void* d_out, int out_size, void* d_ws, size_t ws_size,
                              hipStream_t stream) {
    const float* x  = (const float*)d_in[0];
    const float* cb = (const float*)d_in[1];
    float* out   = (float*)d_out;
    float* idx_f = out + (size_t)BB * DD * TT;

    if (ws_size >= WS_NEED) {
        h16* xth = (h16*)((char*)d_ws + XTH_OFF);
        h16* xtl = (h16*)((char*)d_ws + XTL_OFF);
        h16* cbh = (h16*)((char*)d_ws + CBH_OFF);
        h16* cbl = (h16*)((char*)d_ws + CBL_OFF);
        float* csq = (float*)((char*)d_ws + CSQ_OFF);

        csq_kernel<<<KK / 4, 256, 0, stream>>>(cb, csq);
        split_cb_kernel<<<128, 256, 0, stream>>>(cb, cbh, cbl);
        split_x_kernel<<<dim3(TT / 128, DD / 32, BB), 256, 0, stream>>>(x, xth, xtl);
        mfma_argmin_kernel<<<dim3(TT / 128, BB), 256, 0, stream>>>(
            xth, xtl, cbh, cbl, csq, cb, idx_f, out);
    } else {
        float* csq = (float*)d_ws;
        csq_kernel<<<KK / 4, 256, 0, stream>>>(cb, csq);
        argmin_fp32_kernel<<<dim3(TT / 128, BB), 256, 0, stream>>>(x, cb, csq, idx_f);
        gather_kernel<<<dim3(TT / 256, BB, 4), 256, 0, stream>>>(cb, idx_f, out);
    }
}